// Round 11
// baseline (427.232 us; speedup 1.0000x reference)
//
#include <hip/hip_runtime.h>
#include <math.h>

#define IMGD 224
#define HW 50176      // 224*224
#define NK 100
#define NB 8
#define OUT_PER_B 76800   // 100*16*16*3 = 300*256
#define NCHUNK 131        // chunking of 50176: 129x384 + 2x320
#define MSTR 13           // mask row stride (13 coprime 32: no bank conflicts)

// Session ledger:
// - Cross-block coherence inside a kernel: DEAD (grid.sync ~146us R3).
// - Per-workgroup ramp: DEAD (R2). Fixed ~13us/boundary: DEAD (R4: ~4.4us).
// - Label-in-embed fusion: DEAD (+21us). Residency tail: tiny (R5: -4us).
// - Partials false-sharing: DEAD (R7 neutral). Fused redundant combine: DEAD
//   TWICE (R8: +61us — 528x redundant L2 reads).
// - Wave-ballot pruning: DEAD (R9: +6 — serialized shfl chain LONGER than the
//   parallel 120-thread UB phase; for latency-chain-bound code, minimize the
//   longest dependency chain, not the phase count).
// - R10: INFRA FAILURE (container died twice; kernel never ran). This is a
//   byte-identical resubmit of R10's kernel: R5 config (291.7 best) + ONE
//   change — drop the compaction machinery (ppk/prefix/scatter: 3 phases,
//   ~3 barriers, 9KB LDS). Values stored at their own index t; per-k scan
//   walks mask bits ascending (g asc, ffs asc) => identical ascending-t
//   operand order => partials bit-identical. Count accumulated in-walk.

static __device__ __forceinline__ float ratio_f32() {
  return (float)(10.0 / sqrt(224.0 * 224.0 / 100.0));
}

// distance op sequence — the single source of truth for bit-exactness
static __device__ __forceinline__ float dist5s(float f0, float f1, float f2,
                                               float f3, float f4, float fsq,
                                               float c0, float c1, float c2,
                                               float c3, float c4, float q) {
  float dot = __fmul_rn(f0, c0);
  dot = __fmaf_rn(f1, c1, dot);
  dot = __fmaf_rn(f2, c2, dot);
  dot = __fmaf_rn(f3, c3, dot);
  dot = __fmaf_rn(f4, c4, dot);
  return __fsub_rn(__fadd_rn(fsq, q), __fmul_rn(2.0f, dot));
}

static __device__ __forceinline__ float fsq5(float f0, float f1, float f2,
                                             float f3, float f4) {
  float s = __fmul_rn(f0, f0);
  s = __fadd_rn(s, __fmul_rn(f1, f1));
  s = __fadd_rn(s, __fmul_rn(f2, f2));
  s = __fadd_rn(s, __fmul_rn(f3, f3));
  s = __fadd_rn(s, __fmul_rn(f4, f4));
  return s;
}

// ---------- fused assign+partial: 2 chunks per 256-thread block ----------
// half = tid>>7 picks chunk c = 2*bx + half; lt = tid&127. Centers shared.
// bx==66 blocks (flag==0 grid only): A-setup (bit-exact 128-wide tree).
// Pruning: UB = min_k(dy_max^2+dx_max^2+3), keep k iff clampdist^2 <= UB+1.0;
// candidates walked ascending-k off candm => argmin + ties bit-preserved.
// Scan: values at own index t; thread k walks mask bits ascending t =>
// identical add order to the old compacted scan => bit-exact.
__global__ void __launch_bounds__(256, 4) iter_kernel(
    const float* __restrict__ x, float* __restrict__ centers,
    const float* __restrict__ c2g, float* __restrict__ partials, int flag,
    float* __restrict__ Ag) {
  __shared__ float4 ck4[NK];
  __shared__ float2 ck2[NK];
  __shared__ unsigned int maskS[2][NK * MSTR];
  __shared__ float4 val4[2][384];
  __shared__ float  valf[2][384];
  __shared__ float ubpart[2][12][10];
  __shared__ float ubg[2][12];
  __shared__ unsigned int candm[2][12][4];
  __shared__ float ared[128];
  int bx = blockIdx.x, b = blockIdx.y;
  int tid = threadIdx.x;

  if (bx >= 66) {
    // ---- A-setup block (present only in the flag==0 dispatch) ----
    for (int rr = 0; rr < 2; ++rr) {
      int p = 2 * b + rr;
      float cp = (p + 0.5f) * 14.0f - 0.5f;
      if (tid < 128) {
        // level s=128 of the old 256-wide tree: red[t] = tri(t) + tri(t+128)
        float xd0 = fabsf(cp - (float)tid) / 14.0f;
        float trip0 = fmaxf(0.0f, 1.0f - xd0);
        float trip1 = 0.0f;
        int t2 = tid + 128;
        if (t2 < IMGD) {
          float xd = fabsf(cp - (float)t2) / 14.0f;
          trip1 = fmaxf(0.0f, 1.0f - xd);
        }
        ared[tid] = trip0 + trip1;
      }
      __syncthreads();
      for (int s = 64; s > 0; s >>= 1) {
        if (tid < s) ared[tid] += ared[tid + s];
        __syncthreads();
      }
      float Zp = ared[0];
      __syncthreads();
      if (tid < IMGD) {
        float xd = fabsf(cp - (float)tid) / 14.0f;
        Ag[p * IMGD + tid] = fmaxf(0.0f, 1.0f - xd) / Zp;  // same expr as before
      }
      __syncthreads();
    }
    return;
  }

  int half = tid >> 7;
  int lt = tid & 127;
  int c = 2 * bx + half;
  int start, len;
  if (c < NCHUNK) {
    start = (c < 129) ? c * 384 : 49536 + (c - 129) * 320;
    len   = (c < 129) ? 384 : 320;
  } else {
    start = 0; len = 0;                 // bx==65 half1: inert chunk
  }

  const float ratio = ratio_f32();
  const float* x0 = x + (size_t)b * 3 * HW;
  if (flag == 0) {
    // self-init: same ops as the original setup => identical center values
    if (tid < NK) {
      int gy = tid / 10, gx = tid - 10 * (tid / 10);
      int cy = (int)((gy + 0.5) * 224.0 / 10.0);  // trunc like .astype(int32)
      int cx = (int)((gx + 0.5) * 224.0 / 10.0);
      int i = cy * IMGD + cx;
      float c0 = x0[i], c1 = x0[HW + i], c2 = x0[2 * HW + i];
      float c3 = __fmul_rn((float)cy, ratio);
      float c4 = __fmul_rn((float)cx, ratio);
      float s = __fmul_rn(c0, c0);
      s = __fadd_rn(s, __fmul_rn(c1, c1));
      s = __fadd_rn(s, __fmul_rn(c2, c2));
      s = __fadd_rn(s, __fmul_rn(c3, c3));
      s = __fadd_rn(s, __fmul_rn(c4, c4));
      ck4[tid] = make_float4(c0, c1, c2, c3);
      ck2[tid] = make_float2(c4, s);
      if (bx == 0) {   // persist for combine#1's cnt==0 carryover
        float* oc = centers + ((size_t)b * NK + tid) * 5;
        oc[0] = c0; oc[1] = c1; oc[2] = c2; oc[3] = c3; oc[4] = c4;
      }
    }
  } else {
    const float* cb = centers + (size_t)b * NK * 5;
    const float* c2b = c2g + (size_t)b * NK;
    if (tid < NK) {
      ck4[tid] = make_float4(cb[tid*5+0], cb[tid*5+1], cb[tid*5+2], cb[tid*5+3]);
      ck2[tid] = make_float2(cb[tid*5+4], c2b[tid]);
    }
  }
  for (int t = lt; t < NK * MSTR; t += 128) maskS[half][t] = 0u;
  if (lt < 48) candm[half][lt >> 2][lt & 3] = 0u;

  // pixel loads early (no LDS dependence) — overlap with pruning phases
  float f0[3], f1[3], f2[3], f3[3], f4[3], fq[3];
  bool vld[3];
  for (int r = 0; r < 3; ++r) {
    int t = lt + r * 128;
    vld[r] = (t < len);
    int i = start + (vld[r] ? t : 0);
    int y = i / IMGD, xw = i - y * IMGD;
    f0[r] = x0[i]; f1[r] = x0[HW + i]; f2[r] = x0[2 * HW + i];
    f3[r] = __fmul_rn((float)y, ratio);
    f4[r] = __fmul_rn((float)xw, ratio);
    fq[r] = fsq5(f0[r], f1[r], f2[r], f3[r], f4[r]);
  }
  __syncthreads();

  // UB phase: thread (g,kb) scans 10 centers; group bounds in-register
  if (lt < 120) {
    int g = lt / 10, kb = lt - 10 * g;
    int i0 = start + g * 32, i1 = i0 + 31;
    int ymin = i0 / IMGD, ymax = i1 / IMGD;
    int cmin = (ymin == ymax) ? (i0 - ymin * IMGD) : 0;
    int cmax = (ymin == ymax) ? (i1 - ymax * IMGD) : (IMGD - 1);
    float f3mn = __fmul_rn((float)ymin, ratio);
    float f3mx = __fmul_rn((float)ymax, ratio);
    float f4mn = __fmul_rn((float)cmin, ratio);
    float f4mx = __fmul_rn((float)cmax, ratio);
    float mn = 3.4e38f;
    for (int k = kb * 10; k < kb * 10 + 10; ++k) {
      float c3 = ck4[k].w, c4 = ck2[k].x;
      float dy = fmaxf(fabsf(c3 - f3mn), fabsf(c3 - f3mx));
      float dx = fmaxf(fabsf(c4 - f4mn), fabsf(c4 - f4mx));
      mn = fminf(mn, dy * dy + dx * dx + 3.0f);
    }
    ubpart[half][g][kb] = mn;
  }
  __syncthreads();
  if (lt < 12) {
    float mn = ubpart[half][lt][0];
    for (int j = 1; j < 10; ++j) mn = fminf(mn, ubpart[half][lt][j]);
    ubg[half][lt] = mn + 1.0f;  // slack >> all f32 rounding at these magnitudes
  }
  __syncthreads();
  if (lt < 120) {
    int g = lt / 10, kb = lt - 10 * g;
    int i0 = start + g * 32, i1 = i0 + 31;
    int ymin = i0 / IMGD, ymax = i1 / IMGD;
    int cmin = (ymin == ymax) ? (i0 - ymin * IMGD) : 0;
    int cmax = (ymin == ymax) ? (i1 - ymax * IMGD) : (IMGD - 1);
    float f3mn = __fmul_rn((float)ymin, ratio);
    float f3mx = __fmul_rn((float)ymax, ratio);
    float f4mn = __fmul_rn((float)cmin, ratio);
    float f4mx = __fmul_rn((float)cmax, ratio);
    float lim = ubg[half][g];
    for (int k = kb * 10; k < kb * 10 + 10; ++k) {
      float c3 = ck4[k].w, c4 = ck2[k].x;
      float dy = fmaxf(0.0f, fmaxf(f3mn - c3, c3 - f3mx));
      float dx = fmaxf(0.0f, fmaxf(f4mn - c4, c4 - f4mx));
      if (dy * dy + dx * dx <= lim)
        atomicOr(&candm[half][g][k >> 5], 1u << (k & 31));
    }
  }
  __syncthreads();

  // pruned distance loop straight off the candm bitmask: k ascending;
  // then mask-bit + VALUE store at own index t (no ranks/compaction)
  float best[3]; int bk[3];
  for (int r = 0; r < 3; ++r) {
    best[r] = 3.4e38f; bk[r] = 0;
    int t = lt + r * 128;
    int g = (t < 384) ? (t >> 5) : 0;
    for (int w = 0; w < 4; ++w) {
      unsigned int m = candm[half][g][w];
      while (m) {
        int j = __ffs(m) - 1;
        m &= m - 1;
        int k = (w << 5) + j;
        float4 a4 = ck4[k];
        float2 a2 = ck2[k];
        float d = dist5s(f0[r], f1[r], f2[r], f3[r], f4[r], fq[r],
                         a4.x, a4.y, a4.z, a4.w, a2.x, a2.y);
        if (d < best[r]) { best[r] = d; bk[r] = k; }
      }
    }
  }
  for (int r = 0; r < 3; ++r) {
    int t = lt + r * 128;
    if (vld[r]) {
      atomicOr(&maskS[half][bk[r] * MSTR + (t >> 5)], 1u << (t & 31));
      val4[half][t] = make_float4(f0[r], f1[r], f2[r], f3[r]);
      valf[half][t] = f4[r];
    }
  }
  __syncthreads();

  // scan: thread k walks its mask bits (g asc, ffs asc => t ascending) —
  // identical operand order to the old compacted scan => bit-exact sums.
  if (c < NCHUNK && lt < NK) {
    float s0 = 0.f, s1 = 0.f, s2 = 0.f, s3 = 0.f, s4 = 0.f, s5 = 0.f;
    for (int g = 0; g < 12; ++g) {
      unsigned int m = maskS[half][lt * MSTR + g];
      while (m) {
        int j = __ffs(m) - 1;
        m &= m - 1;
        int t = g * 32 + j;
        float4 vv = val4[half][t];
        float ww = valf[half][t];
        s0 = __fadd_rn(s0, vv.x);
        s1 = __fadd_rn(s1, vv.y);
        s2 = __fadd_rn(s2, vv.z);
        s3 = __fadd_rn(s3, vv.w);
        s4 = __fadd_rn(s4, ww);
        s5 += 1.0f;
      }
    }
    // k-major layout [b][k][j][c]: combine reads contiguous
    float* pp = partials + ((size_t)(b * NK + lt) * 6) * NCHUNK + c;
    pp[0 * NCHUNK] = s0; pp[1 * NCHUNK] = s1; pp[2 * NCHUNK] = s2;
    pp[3 * NCHUNK] = s3; pp[4 * NCHUNK] = s4; pp[5 * NCHUNK] = s5;
  }
}

// ---------- combine: 8 bk-rows per block; LDS-staged 131-chains ----------
// Per-row op order identical to the original 1-row/block version (sequential
// adds chunk0..130; c2 chain sequential) => centers/c2 bit-identical.
__global__ void __launch_bounds__(256) combine_update_kernel(
    float* __restrict__ centers, const float* __restrict__ partials,
    float* __restrict__ c2g) {
  __shared__ float st[8 * 6 * NCHUNK];
  __shared__ float sums[8][6];
  __shared__ float newc[8][5];
  int bb = blockIdx.x;                 // handles bk in [bb*8, bb*8+8)
  int tid = threadIdx.x;
  const float* base = partials + (size_t)bb * 8 * 6 * NCHUNK;
  // 6288 floats = 1572 float4 (both pointers 16B-aligned)
  for (int t = tid; t < (8 * 6 * NCHUNK) / 4; t += 256)
    ((float4*)st)[t] = ((const float4*)base)[t];
  __syncthreads();
  if (tid < 48) {
    int row = tid / 6, comp = tid - 6 * (tid / 6);
    const float* rp = st + (row * 6 + comp) * NCHUNK;
    float s = rp[0];                   // C = 0 + chunk0 (exact)
    for (int c = 1; c < NCHUNK; ++c) s = __fadd_rn(s, rp[c]);
    sums[row][comp] = s;
  }
  __syncthreads();
  if (tid < 40) {
    int row = tid / 5, d = tid - 5 * (tid / 5);
    float cntv = sums[row][5];
    float* cc = centers + (size_t)(bb * 8 + row) * 5;
    float v;
    if (cntv > 0.0f) {                 // where(cnt>0, new, centers)
      float m = fmaxf(cntv, 1.0f);     // np.maximum(cnt,1.0): exact int in f32
      v = __fdiv_rn(sums[row][d], m);
      cc[d] = v;
    } else {
      v = cc[d];                       // unchanged center
    }
    newc[row][d] = v;
  }
  __syncthreads();
  if (tid < 8) {
    // c2 = sum(centers*centers): rounded products, sequential adds
    float t0 = __fmul_rn(newc[tid][0], newc[tid][0]);
    t0 = __fadd_rn(t0, __fmul_rn(newc[tid][1], newc[tid][1]));
    t0 = __fadd_rn(t0, __fmul_rn(newc[tid][2], newc[tid][2]));
    t0 = __fadd_rn(t0, __fmul_rn(newc[tid][3], newc[tid][3]));
    t0 = __fadd_rn(t0, __fmul_rn(newc[tid][4], newc[tid][4]));
    c2g[bb * 8 + tid] = t0;
  }
}

// ---------- labels: final assignment w.r.t. centers_10, written ONCE --------
// Front half of iter (identical loads, pruning bound, dist5s, candidates
// ascending-k from candm) => labels bit-identical to the full argmin.
__global__ void __launch_bounds__(128, 4) label_kernel(
    const float* __restrict__ x, const float* __restrict__ centers,
    const float* __restrict__ c2g, unsigned char* __restrict__ labels) {
  __shared__ float4 ck4[NK];
  __shared__ float2 ck2[NK];
  __shared__ float ubpart[12][10];
  __shared__ float ubg[12];
  __shared__ unsigned int candm[12][4];
  int c = blockIdx.x, b = blockIdx.y;
  int tid = threadIdx.x;
  int start = (c < 129) ? c * 384 : 49536 + (c - 129) * 320;
  int len   = (c < 129) ? 384 : 320;

  const float ratio = ratio_f32();
  const float* x0 = x + (size_t)b * 3 * HW;
  const float* cb = centers + (size_t)b * NK * 5;
  const float* c2b = c2g + (size_t)b * NK;
  if (tid < NK) {
    ck4[tid] = make_float4(cb[tid*5+0], cb[tid*5+1], cb[tid*5+2], cb[tid*5+3]);
    ck2[tid] = make_float2(cb[tid*5+4], c2b[tid]);
  }
  if (tid < 48) candm[tid >> 2][tid & 3] = 0u;

  float f0[3], f1[3], f2[3], f3[3], f4[3], fq[3];
  int ii[3];
  bool vld[3];
  for (int r = 0; r < 3; ++r) {
    int t = tid + r * 128;
    vld[r] = (t < len);
    int i = start + (vld[r] ? t : 0);
    ii[r] = i;
    int y = i / IMGD, xw = i - y * IMGD;
    f0[r] = x0[i]; f1[r] = x0[HW + i]; f2[r] = x0[2 * HW + i];
    f3[r] = __fmul_rn((float)y, ratio);
    f4[r] = __fmul_rn((float)xw, ratio);
    fq[r] = fsq5(f0[r], f1[r], f2[r], f3[r], f4[r]);
  }
  __syncthreads();

  if (tid < 120) {
    int g = tid / 10, kb = tid - 10 * g;
    int i0 = start + g * 32, i1 = i0 + 31;
    int ymin = i0 / IMGD, ymax = i1 / IMGD;
    int cmin = (ymin == ymax) ? (i0 - ymin * IMGD) : 0;
    int cmax = (ymin == ymax) ? (i1 - ymax * IMGD) : (IMGD - 1);
    float f3mn = __fmul_rn((float)ymin, ratio);
    float f3mx = __fmul_rn((float)ymax, ratio);
    float f4mn = __fmul_rn((float)cmin, ratio);
    float f4mx = __fmul_rn((float)cmax, ratio);
    float mn = 3.4e38f;
    for (int k = kb * 10; k < kb * 10 + 10; ++k) {
      float c3 = ck4[k].w, c4 = ck2[k].x;
      float dy = fmaxf(fabsf(c3 - f3mn), fabsf(c3 - f3mx));
      float dx = fmaxf(fabsf(c4 - f4mn), fabsf(c4 - f4mx));
      mn = fminf(mn, dy * dy + dx * dx + 3.0f);
    }
    ubpart[g][kb] = mn;
  }
  __syncthreads();
  if (tid < 12) {
    float mn = ubpart[tid][0];
    for (int j = 1; j < 10; ++j) mn = fminf(mn, ubpart[tid][j]);
    ubg[tid] = mn + 1.0f;
  }
  __syncthreads();
  if (tid < 120) {
    int g = tid / 10, kb = tid - 10 * g;
    int i0 = start + g * 32, i1 = i0 + 31;
    int ymin = i0 / IMGD, ymax = i1 / IMGD;
    int cmin = (ymin == ymax) ? (i0 - ymin * IMGD) : 0;
    int cmax = (ymin == ymax) ? (i1 - ymax * IMGD) : (IMGD - 1);
    float f3mn = __fmul_rn((float)ymin, ratio);
    float f3mx = __fmul_rn((float)ymax, ratio);
    float f4mn = __fmul_rn((float)cmin, ratio);
    float f4mx = __fmul_rn((float)cmax, ratio);
    float lim = ubg[g];
    for (int k = kb * 10; k < kb * 10 + 10; ++k) {
      float c3 = ck4[k].w, c4 = ck2[k].x;
      float dy = fmaxf(0.0f, fmaxf(f3mn - c3, c3 - f3mx));
      float dx = fmaxf(0.0f, fmaxf(f4mn - c4, c4 - f4mx));
      if (dy * dy + dx * dx <= lim)
        atomicOr(&candm[g][k >> 5], 1u << (k & 31));
    }
  }
  __syncthreads();

  float best[3]; int bk[3];
  for (int r = 0; r < 3; ++r) {
    best[r] = 3.4e38f; bk[r] = 0;
    int t = tid + r * 128;
    int g = (t < 384) ? (t >> 5) : 0;
    for (int w = 0; w < 4; ++w) {
      unsigned int m = candm[g][w];
      while (m) {
        int j = __ffs(m) - 1;
        m &= m - 1;
        int k = (w << 5) + j;
        float4 a4 = ck4[k];
        float2 a2 = ck2[k];
        float d = dist5s(f0[r], f1[r], f2[r], f3[r], f4[r], fq[r],
                         a4.x, a4.y, a4.z, a4.w, a2.x, a2.y);
        if (d < best[r]) { best[r] = d; bk[r] = k; }
      }
    }
  }
  unsigned char* lb = labels + (size_t)b * HW;
  for (int r = 0; r < 3; ++r)
    if (vld[r]) lb[ii[r]] = (unsigned char)bk[r];
}

// ---------- embed: block = (b, p, q-group-of-4); A + labels precomputed ----
__global__ void __launch_bounds__(256) embed_kernel(
    const float* __restrict__ x, const unsigned char* __restrict__ labels,
    const float* __restrict__ Ag, float* __restrict__ out) {
  __shared__ float Apv[28];
  __shared__ float Aqw[4][28];
  __shared__ float sk[4][NK * 3];
  int b = blockIdx.y;
  int p = blockIdx.x >> 2;
  int qg = blockIdx.x & 3;
  int q0 = qg * 4;
  int tid = threadIdx.x;

  int h0 = max(0, 14 * p - 7), h1 = min(IMGD - 1, 14 * p + 20);
  int hl = h1 - h0 + 1;
  int w0q[4], w1q[4];
#pragma unroll
  for (int qi = 0; qi < 4; ++qi) {
    int q = q0 + qi;
    w0q[qi] = max(0, 14 * q - 7);
    w1q[qi] = min(IMGD - 1, 14 * q + 20);
  }
  int W0 = w0q[0], W1 = w1q[3];
  int WU = W1 - W0 + 1;

  if (tid < hl) Apv[tid] = Ag[p * IMGD + h0 + tid];
  {
    int t = tid - 64;
    if (t >= 0 && t < 112) {
      int qi = t / 28, dw = t - 28 * qi;
      if (dw <= w1q[qi] - w0q[qi])
        Aqw[qi][dw] = Ag[(q0 + qi) * IMGD + w0q[qi] + dw];
    }
  }
  for (int t = tid; t < 4 * NK * 3; t += 256)
    sk[t / (NK * 3)][t % (NK * 3)] = 0.0f;
  __syncthreads();

  const float* xb = x + (size_t)b * 3 * HW;
  const unsigned char* lb = labels + (size_t)b * HW;
  int n = hl * WU;                    // <= 28*70 = 1960 <= 8*256
  for (int r = 0; r < 8; ++r) {
    int idx = tid + r * 256;
    if (idx >= n) break;
    int dh = idx / WU;
    int dcol = idx - dh * WU;
    int col = W0 + dcol;
    int i = (h0 + dh) * IMGD + col;
    float v0 = xb[i], v1 = xb[HW + i], v2 = xb[2 * HW + i];
    int k = lb[i];
    float ap = Apv[dh];
#pragma unroll
    for (int qi = 0; qi < 4; ++qi) {
      if (col >= w0q[qi] && col <= w1q[qi]) {
        float wgt = ap * Aqw[qi][col - w0q[qi]];
        atomicAdd(&sk[qi][k * 3 + 0], wgt * v0);
        atomicAdd(&sk[qi][k * 3 + 1], wgt * v1);
        atomicAdd(&sk[qi][k * 3 + 2], wgt * v2);
      }
    }
  }
  __syncthreads();

  float* outb = out + (size_t)b * OUT_PER_B;
  for (int t = tid; t < 4 * NK * 3; t += 256) {
    int qi = t / (NK * 3), t3 = t - qi * (NK * 3);
    int k = t3 / 3, cc = t3 - 3 * k;
    int base = p * 48 + (q0 + qi) * 3;
    int f = k * 768 + base + cc;              // flat [K,P,P,C] index
    outb[(f & 255) * 300 + (f >> 8)] = sk[qi][t3]; // view(B,300,256)+transpose
  }
}

extern "C" void kernel_launch(void* const* d_in, const int* in_sizes, int n_in,
                              void* d_out, int out_size, void* d_ws, size_t ws_size,
                              hipStream_t stream) {
  const float* x = (const float*)d_in[0];
  float* out = (float*)d_out;
  char* ws = (char*)d_ws;
  // ws layout:
  float* centers        = (float*)(ws + 16384);      // 16000 B
  float* c2g            = (float*)(ws + 49152);      // 3200 B
  float* Ag             = (float*)(ws + 65536);      // 16*224*4 = 14336 B
  unsigned char* labels = (unsigned char*)(ws + 98304); // 8*50176 = 401408 B
  float* partials       = (float*)(ws + 1703936);    // 8*100*6*131*4 = 2515200 B

  dim3 ig0(67, NB);               // bx 0..65: chunk pairs; bx 66: A-setup
  dim3 ig(66, NB);                // 528 blocks — all resident at 4 blocks/CU
  iter_kernel<<<ig0, 256, 0, stream>>>(x, centers, c2g, partials, 0, Ag);
  combine_update_kernel<<<NB * NK / 8, 256, 0, stream>>>(centers, partials, c2g);
  for (int it = 1; it < 10; ++it) {
    iter_kernel<<<ig, 256, 0, stream>>>(x, centers, c2g, partials, 1, Ag);
    combine_update_kernel<<<NB * NK / 8, 256, 0, stream>>>(centers, partials, c2g);
  }
  label_kernel<<<dim3(NCHUNK, NB), 128, 0, stream>>>(x, centers, c2g, labels);
  dim3 egrid(64, NB);             // (p*4 + qgroup) x b — 512 blocks
  embed_kernel<<<egrid, 256, 0, stream>>>(x, labels, Ag, out);
}

// Round 12
// 292.497 us; speedup vs baseline: 1.4606x; 1.4606x over previous
//
#include <hip/hip_runtime.h>
#include <math.h>

#define IMGD 224
#define HW 50176      // 224*224
#define NK 100
#define NB 8
#define OUT_PER_B 76800   // 100*16*16*3 = 300*256
#define NCHUNK 131        // chunking of 50176: 129x384 + 2x320
#define MSTR 13           // mask/ppk row stride (13 coprime 32: no bank conflicts)

// FINAL session ledger (R0-R11):
// - Cross-block coherence inside a kernel: DEAD (grid.sync ~146us R3; fences
//   ~1.5us/block prior session). Kernel boundary = only cheap coherence point.
// - Per-workgroup ramp: DEAD (R2). Fixed ~13us/boundary: DEAD (R4: ~4.4us).
// - Label-in-embed fusion: DEAD (+21us). Residency tail: small (R5: -4us).
// - Partials false-sharing: DEAD (R7 neutral). Fused redundant combine: DEAD
//   TWICE (R8: +61us — 528x redundant L2 reads).
// - Wave-ballot pruning: DEAD (R9: +6us). Compaction-removal: DEAD (R11:
//   +135us — mask-walk scan serializes LDS loads behind ffs; the compacted
//   scan's upfront-computable contiguous addresses are what lets the compiler
//   pipeline it. Shorter-but-serial loses to longer-but-pipelined.)
// - STRUCTURAL FLOOR ~290us: 10 data-dependent k-means iterations force 22
//   coherence points x ~4.4us + 11 iter bodies x ~10.2us latency-chain
//   (VALUBusy 31%, occupancy-invariant) + combines/label/embed. No resource
//   roofline (HBM 5%, VALU 31%); the limit is dependency latency, and every
//   measured alternative to this dispatch structure was slower.
// This file = R5 config, the session's best (291.7us, absmax 0.001953125).

static __device__ __forceinline__ float ratio_f32() {
  return (float)(10.0 / sqrt(224.0 * 224.0 / 100.0));
}

// distance op sequence — the single source of truth for bit-exactness
static __device__ __forceinline__ float dist5s(float f0, float f1, float f2,
                                               float f3, float f4, float fsq,
                                               float c0, float c1, float c2,
                                               float c3, float c4, float q) {
  float dot = __fmul_rn(f0, c0);
  dot = __fmaf_rn(f1, c1, dot);
  dot = __fmaf_rn(f2, c2, dot);
  dot = __fmaf_rn(f3, c3, dot);
  dot = __fmaf_rn(f4, c4, dot);
  return __fsub_rn(__fadd_rn(fsq, q), __fmul_rn(2.0f, dot));
}

static __device__ __forceinline__ float fsq5(float f0, float f1, float f2,
                                             float f3, float f4) {
  float s = __fmul_rn(f0, f0);
  s = __fadd_rn(s, __fmul_rn(f1, f1));
  s = __fadd_rn(s, __fmul_rn(f2, f2));
  s = __fadd_rn(s, __fmul_rn(f3, f3));
  s = __fadd_rn(s, __fmul_rn(f4, f4));
  return s;
}

// ---------- fused assign+partial: 2 chunks per 256-thread block ----------
// half = tid>>7 picks chunk c = 2*bx + half; lt = tid&127 runs the per-chunk
// code with chunk-local LDS indexed [half]. Centers shared (same b).
// bx==66 blocks (flag==0 grid only) materialize resize-matrix rows 2b,2b+1
// into Ag (identical 128-wide tree pairing => A bit-identical).
// Pruning: UB = min_k(dy_max^2+dx_max^2+3), keep k iff dy_min^2+dx_min^2 <=
// UB+1.0 (slack >> f32 rounding); candidates walked ascending-k straight out
// of the candm bitmask => argmin + first-index ties bit-preserved.
__global__ void __launch_bounds__(256, 4) iter_kernel(
    const float* __restrict__ x, float* __restrict__ centers,
    const float* __restrict__ c2g, float* __restrict__ partials, int flag,
    float* __restrict__ Ag) {
  __shared__ float4 ck4[NK];
  __shared__ float2 ck2[NK];
  __shared__ unsigned int maskS[2][NK * MSTR];
  __shared__ unsigned short ppkS[2][NK * MSTR];
  __shared__ float4 cval4[2][384];
  __shared__ float  cvalf[2][384];
  __shared__ int cntS[2][128];
  __shared__ int offxS[2][128];
  __shared__ int wtotS[2];
  __shared__ float ubpart[2][12][10];
  __shared__ float ubg[2][12];
  __shared__ unsigned int candm[2][12][4];
  __shared__ float ared[128];
  int bx = blockIdx.x, b = blockIdx.y;
  int tid = threadIdx.x;

  if (bx >= 66) {
    // ---- A-setup block (present only in the flag==0 dispatch) ----
    for (int rr = 0; rr < 2; ++rr) {
      int p = 2 * b + rr;
      float cp = (p + 0.5f) * 14.0f - 0.5f;
      if (tid < 128) {
        // level s=128 of the old 256-wide tree: red[t] = tri(t) + tri(t+128)
        float xd0 = fabsf(cp - (float)tid) / 14.0f;
        float trip0 = fmaxf(0.0f, 1.0f - xd0);
        float trip1 = 0.0f;
        int t2 = tid + 128;
        if (t2 < IMGD) {
          float xd = fabsf(cp - (float)t2) / 14.0f;
          trip1 = fmaxf(0.0f, 1.0f - xd);
        }
        ared[tid] = trip0 + trip1;
      }
      __syncthreads();
      for (int s = 64; s > 0; s >>= 1) {
        if (tid < s) ared[tid] += ared[tid + s];
        __syncthreads();
      }
      float Zp = ared[0];
      __syncthreads();
      if (tid < IMGD) {
        float xd = fabsf(cp - (float)tid) / 14.0f;
        Ag[p * IMGD + tid] = fmaxf(0.0f, 1.0f - xd) / Zp;  // same expr as before
      }
      __syncthreads();
    }
    return;
  }

  int half = tid >> 7;
  int lt = tid & 127;
  int c = 2 * bx + half;
  int start, len;
  if (c < NCHUNK) {
    start = (c < 129) ? c * 384 : 49536 + (c - 129) * 320;
    len   = (c < 129) ? 384 : 320;
  } else {
    start = 0; len = 0;                 // bx==65 half1: inert chunk
  }

  const float ratio = ratio_f32();
  const float* x0 = x + (size_t)b * 3 * HW;
  if (flag == 0) {
    // self-init: same ops as the original setup => identical center values
    if (tid < NK) {
      int gy = tid / 10, gx = tid - 10 * (tid / 10);
      int cy = (int)((gy + 0.5) * 224.0 / 10.0);  // trunc like .astype(int32)
      int cx = (int)((gx + 0.5) * 224.0 / 10.0);
      int i = cy * IMGD + cx;
      float c0 = x0[i], c1 = x0[HW + i], c2 = x0[2 * HW + i];
      float c3 = __fmul_rn((float)cy, ratio);
      float c4 = __fmul_rn((float)cx, ratio);
      float s = __fmul_rn(c0, c0);
      s = __fadd_rn(s, __fmul_rn(c1, c1));
      s = __fadd_rn(s, __fmul_rn(c2, c2));
      s = __fadd_rn(s, __fmul_rn(c3, c3));
      s = __fadd_rn(s, __fmul_rn(c4, c4));
      ck4[tid] = make_float4(c0, c1, c2, c3);
      ck2[tid] = make_float2(c4, s);
      if (bx == 0) {   // persist for combine#1's cnt==0 carryover
        float* oc = centers + ((size_t)b * NK + tid) * 5;
        oc[0] = c0; oc[1] = c1; oc[2] = c2; oc[3] = c3; oc[4] = c4;
      }
    }
  } else {
    const float* cb = centers + (size_t)b * NK * 5;
    const float* c2b = c2g + (size_t)b * NK;
    if (tid < NK) {
      ck4[tid] = make_float4(cb[tid*5+0], cb[tid*5+1], cb[tid*5+2], cb[tid*5+3]);
      ck2[tid] = make_float2(cb[tid*5+4], c2b[tid]);
    }
  }
  for (int t = lt; t < NK * MSTR; t += 128) maskS[half][t] = 0u;
  if (lt < 48) candm[half][lt >> 2][lt & 3] = 0u;

  // pixel loads early (no LDS dependence) — overlap with pruning phases
  float f0[3], f1[3], f2[3], f3[3], f4[3], fq[3];
  bool vld[3];
  for (int r = 0; r < 3; ++r) {
    int t = lt + r * 128;
    vld[r] = (t < len);
    int i = start + (vld[r] ? t : 0);
    int y = i / IMGD, xw = i - y * IMGD;
    f0[r] = x0[i]; f1[r] = x0[HW + i]; f2[r] = x0[2 * HW + i];
    f3[r] = __fmul_rn((float)y, ratio);
    f4[r] = __fmul_rn((float)xw, ratio);
    fq[r] = fsq5(f0[r], f1[r], f2[r], f3[r], f4[r]);
  }
  __syncthreads();

  // UB phase: thread (g,kb) scans 10 centers; group bounds in-register
  if (lt < 120) {
    int g = lt / 10, kb = lt - 10 * g;
    int i0 = start + g * 32, i1 = i0 + 31;
    int ymin = i0 / IMGD, ymax = i1 / IMGD;
    int cmin = (ymin == ymax) ? (i0 - ymin * IMGD) : 0;
    int cmax = (ymin == ymax) ? (i1 - ymax * IMGD) : (IMGD - 1);
    float f3mn = __fmul_rn((float)ymin, ratio);
    float f3mx = __fmul_rn((float)ymax, ratio);
    float f4mn = __fmul_rn((float)cmin, ratio);
    float f4mx = __fmul_rn((float)cmax, ratio);
    float mn = 3.4e38f;
    for (int k = kb * 10; k < kb * 10 + 10; ++k) {
      float c3 = ck4[k].w, c4 = ck2[k].x;
      float dy = fmaxf(fabsf(c3 - f3mn), fabsf(c3 - f3mx));
      float dx = fmaxf(fabsf(c4 - f4mn), fabsf(c4 - f4mx));
      mn = fminf(mn, dy * dy + dx * dx + 3.0f);
    }
    ubpart[half][g][kb] = mn;
  }
  __syncthreads();
  if (lt < 12) {
    float mn = ubpart[half][lt][0];
    for (int j = 1; j < 10; ++j) mn = fminf(mn, ubpart[half][lt][j]);
    ubg[half][lt] = mn + 1.0f;  // slack >> all f32 rounding at these magnitudes
  }
  __syncthreads();
  if (lt < 120) {
    int g = lt / 10, kb = lt - 10 * g;
    int i0 = start + g * 32, i1 = i0 + 31;
    int ymin = i0 / IMGD, ymax = i1 / IMGD;
    int cmin = (ymin == ymax) ? (i0 - ymin * IMGD) : 0;
    int cmax = (ymin == ymax) ? (i1 - ymax * IMGD) : (IMGD - 1);
    float f3mn = __fmul_rn((float)ymin, ratio);
    float f3mx = __fmul_rn((float)ymax, ratio);
    float f4mn = __fmul_rn((float)cmin, ratio);
    float f4mx = __fmul_rn((float)cmax, ratio);
    float lim = ubg[half][g];
    for (int k = kb * 10; k < kb * 10 + 10; ++k) {
      float c3 = ck4[k].w, c4 = ck2[k].x;
      float dy = fmaxf(0.0f, fmaxf(f3mn - c3, c3 - f3mx));
      float dx = fmaxf(0.0f, fmaxf(f4mn - c4, c4 - f4mx));
      if (dy * dy + dx * dx <= lim)
        atomicOr(&candm[half][g][k >> 5], 1u << (k & 31));
    }
  }
  __syncthreads();

  // pruned distance loop straight off the candm bitmask: k ascending
  float best[3]; int bk[3];
  for (int r = 0; r < 3; ++r) {
    best[r] = 3.4e38f; bk[r] = 0;
    int t = lt + r * 128;
    int g = (t < 384) ? (t >> 5) : 0;
    for (int w = 0; w < 4; ++w) {
      unsigned int m = candm[half][g][w];
      while (m) {
        int j = __ffs(m) - 1;
        m &= m - 1;
        int k = (w << 5) + j;
        float4 a4 = ck4[k];
        float2 a2 = ck2[k];
        float d = dist5s(f0[r], f1[r], f2[r], f3[r], f4[r], fq[r],
                         a4.x, a4.y, a4.z, a4.w, a2.x, a2.y);
        if (d < best[r]) { best[r] = d; bk[r] = k; }
      }
    }
  }
  for (int r = 0; r < 3; ++r) {
    int t = lt + r * 128;
    if (vld[r]) atomicOr(&maskS[half][bk[r] * MSTR + (t >> 5)], 1u << (t & 31));
  }
  __syncthreads();

  // per-k cumulative popcounts (stride-13 rows: conflict-free)
  int myCnt = 0;
  if (lt < NK) {
    int s = 0;
    for (int g = 0; g < 12; ++g) {
      ppkS[half][lt * MSTR + g] = (unsigned short)s;
      s += __popc(maskS[half][lt * MSTR + g]);
    }
    myCnt = s;
  }
  cntS[half][lt] = myCnt;
  __syncthreads();

  // inclusive prefix over 128 counts per half: shfl per wave + cross-wave fixup
  int v = myCnt;
  for (int d = 1; d < 64; d <<= 1) {
    int u = __shfl_up(v, d, 64);
    if ((tid & 63) >= d) v += u;
  }
  if (lt == 63) wtotS[half] = v;
  __syncthreads();
  if (lt >= 64) v += wtotS[half];
  offxS[half][lt] = v;
  __syncthreads();

  // stable VALUE scatter: pos = (off[k]-cnt[k]) + rank_within_k(t)
  for (int r = 0; r < 3; ++r) {
    int t = lt + r * 128;
    if (vld[r]) {
      int g = t >> 5, j = t & 31;
      unsigned int m = maskS[half][bk[r] * MSTR + g];
      int rank = ppkS[half][bk[r] * MSTR + g] + __popc(m & ((1u << j) - 1u));
      int pos = offxS[half][bk[r]] - cntS[half][bk[r]] + rank;
      cval4[half][pos] = make_float4(f0[r], f1[r], f2[r], f3[r]);
      cvalf[half][pos] = f4[r];
    }
  }
  __syncthreads();

  // scan: thread k walks its consecutive compacted range (ascending t)
  if (c < NCHUNK && lt < NK) {
    int n = cntS[half][lt];
    int base = offxS[half][lt] - n;
    float s0 = 0.f, s1 = 0.f, s2 = 0.f, s3 = 0.f, s4 = 0.f, s5 = 0.f;
    for (int m = 0; m < n; ++m) {
      float4 vv = cval4[half][base + m];
      float ww = cvalf[half][base + m];
      s0 = __fadd_rn(s0, vv.x);
      s1 = __fadd_rn(s1, vv.y);
      s2 = __fadd_rn(s2, vv.z);
      s3 = __fadd_rn(s3, vv.w);
      s4 = __fadd_rn(s4, ww);
      s5 += 1.0f;
    }
    // k-major layout [b][k][j][c]: combine reads contiguous
    float* pp = partials + ((size_t)(b * NK + lt) * 6) * NCHUNK + c;
    pp[0 * NCHUNK] = s0; pp[1 * NCHUNK] = s1; pp[2 * NCHUNK] = s2;
    pp[3 * NCHUNK] = s3; pp[4 * NCHUNK] = s4; pp[5 * NCHUNK] = s5;
  }
}

// ---------- combine: 8 bk-rows per block; LDS-staged 131-chains ----------
// Per-row op order identical to the original 1-row/block version (sequential
// adds chunk0..130; c2 chain sequential) => centers/c2 bit-identical.
__global__ void __launch_bounds__(256) combine_update_kernel(
    float* __restrict__ centers, const float* __restrict__ partials,
    float* __restrict__ c2g) {
  __shared__ float st[8 * 6 * NCHUNK];
  __shared__ float sums[8][6];
  __shared__ float newc[8][5];
  int bb = blockIdx.x;                 // handles bk in [bb*8, bb*8+8)
  int tid = threadIdx.x;
  const float* base = partials + (size_t)bb * 8 * 6 * NCHUNK;
  // 6288 floats = 1572 float4 (both pointers 16B-aligned)
  for (int t = tid; t < (8 * 6 * NCHUNK) / 4; t += 256)
    ((float4*)st)[t] = ((const float4*)base)[t];
  __syncthreads();
  if (tid < 48) {
    int row = tid / 6, comp = tid - 6 * (tid / 6);
    const float* rp = st + (row * 6 + comp) * NCHUNK;
    float s = rp[0];                   // C = 0 + chunk0 (exact)
    for (int c = 1; c < NCHUNK; ++c) s = __fadd_rn(s, rp[c]);
    sums[row][comp] = s;
  }
  __syncthreads();
  if (tid < 40) {
    int row = tid / 5, d = tid - 5 * (tid / 5);
    float cntv = sums[row][5];
    float* cc = centers + (size_t)(bb * 8 + row) * 5;
    float v;
    if (cntv > 0.0f) {                 // where(cnt>0, new, centers)
      float m = fmaxf(cntv, 1.0f);     // np.maximum(cnt,1.0): exact int in f32
      v = __fdiv_rn(sums[row][d], m);
      cc[d] = v;
    } else {
      v = cc[d];                       // unchanged center
    }
    newc[row][d] = v;
  }
  __syncthreads();
  if (tid < 8) {
    // c2 = sum(centers*centers): rounded products, sequential adds
    float t0 = __fmul_rn(newc[tid][0], newc[tid][0]);
    t0 = __fadd_rn(t0, __fmul_rn(newc[tid][1], newc[tid][1]));
    t0 = __fadd_rn(t0, __fmul_rn(newc[tid][2], newc[tid][2]));
    t0 = __fadd_rn(t0, __fmul_rn(newc[tid][3], newc[tid][3]));
    t0 = __fadd_rn(t0, __fmul_rn(newc[tid][4], newc[tid][4]));
    c2g[bb * 8 + tid] = t0;
  }
}

// ---------- labels: final assignment w.r.t. centers_10, written ONCE --------
// Front half of iter (identical loads, pruning bound, dist5s, candidates
// ascending-k from candm) => labels bit-identical to the full argmin.
__global__ void __launch_bounds__(128, 4) label_kernel(
    const float* __restrict__ x, const float* __restrict__ centers,
    const float* __restrict__ c2g, unsigned char* __restrict__ labels) {
  __shared__ float4 ck4[NK];
  __shared__ float2 ck2[NK];
  __shared__ float ubpart[12][10];
  __shared__ float ubg[12];
  __shared__ unsigned int candm[12][4];
  int c = blockIdx.x, b = blockIdx.y;
  int tid = threadIdx.x;
  int start = (c < 129) ? c * 384 : 49536 + (c - 129) * 320;
  int len   = (c < 129) ? 384 : 320;

  const float ratio = ratio_f32();
  const float* x0 = x + (size_t)b * 3 * HW;
  const float* cb = centers + (size_t)b * NK * 5;
  const float* c2b = c2g + (size_t)b * NK;
  if (tid < NK) {
    ck4[tid] = make_float4(cb[tid*5+0], cb[tid*5+1], cb[tid*5+2], cb[tid*5+3]);
    ck2[tid] = make_float2(cb[tid*5+4], c2b[tid]);
  }
  if (tid < 48) candm[tid >> 2][tid & 3] = 0u;

  float f0[3], f1[3], f2[3], f3[3], f4[3], fq[3];
  int ii[3];
  bool vld[3];
  for (int r = 0; r < 3; ++r) {
    int t = tid + r * 128;
    vld[r] = (t < len);
    int i = start + (vld[r] ? t : 0);
    ii[r] = i;
    int y = i / IMGD, xw = i - y * IMGD;
    f0[r] = x0[i]; f1[r] = x0[HW + i]; f2[r] = x0[2 * HW + i];
    f3[r] = __fmul_rn((float)y, ratio);
    f4[r] = __fmul_rn((float)xw, ratio);
    fq[r] = fsq5(f0[r], f1[r], f2[r], f3[r], f4[r]);
  }
  __syncthreads();

  if (tid < 120) {
    int g = tid / 10, kb = tid - 10 * g;
    int i0 = start + g * 32, i1 = i0 + 31;
    int ymin = i0 / IMGD, ymax = i1 / IMGD;
    int cmin = (ymin == ymax) ? (i0 - ymin * IMGD) : 0;
    int cmax = (ymin == ymax) ? (i1 - ymax * IMGD) : (IMGD - 1);
    float f3mn = __fmul_rn((float)ymin, ratio);
    float f3mx = __fmul_rn((float)ymax, ratio);
    float f4mn = __fmul_rn((float)cmin, ratio);
    float f4mx = __fmul_rn((float)cmax, ratio);
    float mn = 3.4e38f;
    for (int k = kb * 10; k < kb * 10 + 10; ++k) {
      float c3 = ck4[k].w, c4 = ck2[k].x;
      float dy = fmaxf(fabsf(c3 - f3mn), fabsf(c3 - f3mx));
      float dx = fmaxf(fabsf(c4 - f4mn), fabsf(c4 - f4mx));
      mn = fminf(mn, dy * dy + dx * dx + 3.0f);
    }
    ubpart[g][kb] = mn;
  }
  __syncthreads();
  if (tid < 12) {
    float mn = ubpart[tid][0];
    for (int j = 1; j < 10; ++j) mn = fminf(mn, ubpart[tid][j]);
    ubg[tid] = mn + 1.0f;
  }
  __syncthreads();
  if (tid < 120) {
    int g = tid / 10, kb = tid - 10 * g;
    int i0 = start + g * 32, i1 = i0 + 31;
    int ymin = i0 / IMGD, ymax = i1 / IMGD;
    int cmin = (ymin == ymax) ? (i0 - ymin * IMGD) : 0;
    int cmax = (ymin == ymax) ? (i1 - ymax * IMGD) : (IMGD - 1);
    float f3mn = __fmul_rn((float)ymin, ratio);
    float f3mx = __fmul_rn((float)ymax, ratio);
    float f4mn = __fmul_rn((float)cmin, ratio);
    float f4mx = __fmul_rn((float)cmax, ratio);
    float lim = ubg[g];
    for (int k = kb * 10; k < kb * 10 + 10; ++k) {
      float c3 = ck4[k].w, c4 = ck2[k].x;
      float dy = fmaxf(0.0f, fmaxf(f3mn - c3, c3 - f3mx));
      float dx = fmaxf(0.0f, fmaxf(f4mn - c4, c4 - f4mx));
      if (dy * dy + dx * dx <= lim)
        atomicOr(&candm[g][k >> 5], 1u << (k & 31));
    }
  }
  __syncthreads();

  float best[3]; int bk[3];
  for (int r = 0; r < 3; ++r) {
    best[r] = 3.4e38f; bk[r] = 0;
    int t = tid + r * 128;
    int g = (t < 384) ? (t >> 5) : 0;
    for (int w = 0; w < 4; ++w) {
      unsigned int m = candm[g][w];
      while (m) {
        int j = __ffs(m) - 1;
        m &= m - 1;
        int k = (w << 5) + j;
        float4 a4 = ck4[k];
        float2 a2 = ck2[k];
        float d = dist5s(f0[r], f1[r], f2[r], f3[r], f4[r], fq[r],
                         a4.x, a4.y, a4.z, a4.w, a2.x, a2.y);
        if (d < best[r]) { best[r] = d; bk[r] = k; }
      }
    }
  }
  unsigned char* lb = labels + (size_t)b * HW;
  for (int r = 0; r < 3; ++r)
    if (vld[r]) lb[ii[r]] = (unsigned char)bk[r];
}

// ---------- embed: block = (b, p, q-group-of-4); A + labels precomputed ----
__global__ void __launch_bounds__(256) embed_kernel(
    const float* __restrict__ x, const unsigned char* __restrict__ labels,
    const float* __restrict__ Ag, float* __restrict__ out) {
  __shared__ float Apv[28];
  __shared__ float Aqw[4][28];
  __shared__ float sk[4][NK * 3];
  int b = blockIdx.y;
  int p = blockIdx.x >> 2;
  int qg = blockIdx.x & 3;
  int q0 = qg * 4;
  int tid = threadIdx.x;

  int h0 = max(0, 14 * p - 7), h1 = min(IMGD - 1, 14 * p + 20);
  int hl = h1 - h0 + 1;
  int w0q[4], w1q[4];
#pragma unroll
  for (int qi = 0; qi < 4; ++qi) {
    int q = q0 + qi;
    w0q[qi] = max(0, 14 * q - 7);
    w1q[qi] = min(IMGD - 1, 14 * q + 20);
  }
  int W0 = w0q[0], W1 = w1q[3];
  int WU = W1 - W0 + 1;

  if (tid < hl) Apv[tid] = Ag[p * IMGD + h0 + tid];
  {
    int t = tid - 64;
    if (t >= 0 && t < 112) {
      int qi = t / 28, dw = t - 28 * qi;
      if (dw <= w1q[qi] - w0q[qi])
        Aqw[qi][dw] = Ag[(q0 + qi) * IMGD + w0q[qi] + dw];
    }
  }
  for (int t = tid; t < 4 * NK * 3; t += 256)
    sk[t / (NK * 3)][t % (NK * 3)] = 0.0f;
  __syncthreads();

  const float* xb = x + (size_t)b * 3 * HW;
  const unsigned char* lb = labels + (size_t)b * HW;
  int n = hl * WU;                    // <= 28*70 = 1960 <= 8*256
  for (int r = 0; r < 8; ++r) {
    int idx = tid + r * 256;
    if (idx >= n) break;
    int dh = idx / WU;
    int dcol = idx - dh * WU;
    int col = W0 + dcol;
    int i = (h0 + dh) * IMGD + col;
    float v0 = xb[i], v1 = xb[HW + i], v2 = xb[2 * HW + i];
    int k = lb[i];
    float ap = Apv[dh];
#pragma unroll
    for (int qi = 0; qi < 4; ++qi) {
      if (col >= w0q[qi] && col <= w1q[qi]) {
        float wgt = ap * Aqw[qi][col - w0q[qi]];
        atomicAdd(&sk[qi][k * 3 + 0], wgt * v0);
        atomicAdd(&sk[qi][k * 3 + 1], wgt * v1);
        atomicAdd(&sk[qi][k * 3 + 2], wgt * v2);
      }
    }
  }
  __syncthreads();

  float* outb = out + (size_t)b * OUT_PER_B;
  for (int t = tid; t < 4 * NK * 3; t += 256) {
    int qi = t / (NK * 3), t3 = t - qi * (NK * 3);
    int k = t3 / 3, cc = t3 - 3 * k;
    int base = p * 48 + (q0 + qi) * 3;
    int f = k * 768 + base + cc;              // flat [K,P,P,C] index
    outb[(f & 255) * 300 + (f >> 8)] = sk[qi][t3]; // view(B,300,256)+transpose
  }
}

extern "C" void kernel_launch(void* const* d_in, const int* in_sizes, int n_in,
                              void* d_out, int out_size, void* d_ws, size_t ws_size,
                              hipStream_t stream) {
  const float* x = (const float*)d_in[0];
  float* out = (float*)d_out;
  char* ws = (char*)d_ws;
  // ws layout:
  float* centers        = (float*)(ws + 16384);      // 16000 B
  float* c2g            = (float*)(ws + 49152);      // 3200 B
  float* Ag             = (float*)(ws + 65536);      // 16*224*4 = 14336 B
  unsigned char* labels = (unsigned char*)(ws + 98304); // 8*50176 = 401408 B
  float* partials       = (float*)(ws + 1703936);    // 8*100*6*131*4 = 2515200 B

  dim3 ig0(67, NB);               // bx 0..65: chunk pairs; bx 66: A-setup
  dim3 ig(66, NB);                // 528 blocks — all resident at 4 blocks/CU
  iter_kernel<<<ig0, 256, 0, stream>>>(x, centers, c2g, partials, 0, Ag);
  combine_update_kernel<<<NB * NK / 8, 256, 0, stream>>>(centers, partials, c2g);
  for (int it = 1; it < 10; ++it) {
    iter_kernel<<<ig, 256, 0, stream>>>(x, centers, c2g, partials, 1, Ag);
    combine_update_kernel<<<NB * NK / 8, 256, 0, stream>>>(centers, partials, c2g);
  }
  label_kernel<<<dim3(NCHUNK, NB), 128, 0, stream>>>(x, centers, c2g, labels);
  dim3 egrid(64, NB);             // (p*4 + qgroup) x b — 512 blocks
  embed_kernel<<<egrid, 256, 0, stream>>>(x, labels, Ag, out);
}